// Round 13
// baseline (354.013 us; speedup 1.0000x reference)
//
#include <hip/hip_runtime.h>
#include <hip/hip_bf16.h>
#include <cmath>

#define BETA 0.3f
#define LAMBDA_PHY 0.15f

#define BM 128
#define BN 128
#define BK 32
#define NT 256

typedef __bf16 bf16x8 __attribute__((ext_vector_type(8)));
typedef float f32x4 __attribute__((ext_vector_type(4)));

#define AS1 __attribute__((address_space(1)))
#define AS3 __attribute__((address_space(3)))

#define FENCE() asm volatile("" ::: "memory")
#define BARRIER() do { FENCE(); __builtin_amdgcn_s_barrier(); FENCE(); } while (0)
#define WAITV4() asm volatile("s_waitcnt vmcnt(4)" ::: "memory")
#define WAITV0() asm volatile("s_waitcnt vmcnt(0)" ::: "memory")

__device__ __forceinline__ unsigned short f2bf_rn(float f) {
    unsigned int u = __builtin_bit_cast(unsigned int, f);
    return (unsigned short)((u + 0x7FFFu + ((u >> 16) & 1u)) >> 16);
}

__device__ __forceinline__ float bf2f(unsigned short u) {
    return __builtin_bit_cast(float, (unsigned int)u << 16);
}

__device__ __forceinline__ float softplus_f(float x) {
    return fmaxf(x, 0.0f) + __logf(1.0f + __expf(-fabsf(x)));
}

__device__ __forceinline__ float smooth_l1_f(float d) {
    float ad = fabsf(d);
    return (ad < BETA) ? (0.5f / BETA) * d * d : (ad - 0.5f * BETA);
}

// ---------------------------------------------------------------------------
// Kernel 1 (fused): blocks [0,Z): adjacency row -> bf16 mask + invdeg + hasnb.
//                   blocks [Z, Z+ncb): fp32->bf16 conv of ctemps (grid-stride).
__global__ void k_prepconv(const int* __restrict__ adj, unsigned short* __restrict__ maskbf,
                           float* __restrict__ invdeg, float* __restrict__ hasnb, int Z,
                           const float* __restrict__ src, uint4* __restrict__ dst,
                           long n8, int ncb) {
    int t = threadIdx.x;
    if ((int)blockIdx.x < Z) {
        int z = blockIdx.x;
        const int* row = adj + (size_t)z * Z;
        unsigned short* mrow = maskbf + (size_t)z * Z;
        int cnt = 0;
        for (int n = t; n < Z; n += blockDim.x) {
            int a = (row[n] > 0);
            mrow[n] = a ? (unsigned short)0x3F80 : (unsigned short)0;  // bf16 1.0/0.0
            cnt += a;
        }
        for (int o = 32; o; o >>= 1) cnt += __shfl_down(cnt, o);
        __shared__ int rs[4];
        int lane = t & 63, wave = t >> 6;
        if (lane == 0) rs[wave] = cnt;
        __syncthreads();
        if (t == 0) {
            int deg = rs[0] + rs[1] + rs[2] + rs[3];
            invdeg[z] = (deg > 0) ? 1.0f / (float)deg : 1.0f;
            hasnb[z]  = (deg > 0) ? 1.0f : 0.0f;
        }
    } else {
        long i = (long)(blockIdx.x - Z) * blockDim.x + t;
        long stride = (long)ncb * blockDim.x;
        for (; i < n8; i += stride) {
            const float4* s = (const float4*)(src + i * 8);
            float4 a = s[0], b = s[1];
            uint4 o;
            o.x = (unsigned)f2bf_rn(a.x) | ((unsigned)f2bf_rn(a.y) << 16);
            o.y = (unsigned)f2bf_rn(a.z) | ((unsigned)f2bf_rn(a.w) << 16);
            o.z = (unsigned)f2bf_rn(b.x) | ((unsigned)f2bf_rn(b.y) << 16);
            o.w = (unsigned)f2bf_rn(b.z) | ((unsigned)f2bf_rn(b.w) << 16);
            dst[i] = o;
        }
    }
}

// ---------------------------------------------------------------------------
// Kernel 2: 128x128 bf16 GEMM, BK=32, 4 waves (2x2), per-wave 64x64.
// Round-13: 32.3 KB LDS -> FOUR independent blocks/CU (16 waves/CU, 4 barrier
// groups). Prior rounds never exceeded 2 blocks/CU; all waves of a block are
// phase-locked, so 2 groups rarely anti-phase -> MFMA/VALU/stall each ~30%.
// 4 groups decorrelate phases: one block's ds_read/epilogue-HBM hides under
// another's MFMA. Keeps R10 wins: compile-time buffer unroll, loop-invariant
// LDS offsets, counted vmcnt(4), src-side T2 swizzle (slot^=row&3, 4 slots/row
// -> 2-way = free), T1 XCD swizzle, setprio.
// Registers: acc[4][4]=64 AGPR + transient af[4]+bv[4] (32) + addr ~ 115
// <= 128 cap from __launch_bounds__(256,4).
__global__ __launch_bounds__(NT, 4) void k_gemm(
    const unsigned short* __restrict__ Abf,   // [M][K] bf16 ctemps
    const unsigned short* __restrict__ Bbf,   // [N][K] bf16 mask
    const float* __restrict__ preds,
    const float* __restrict__ targets,
    const float* __restrict__ invdeg,
    const float* __restrict__ hasnb,
    float* __restrict__ partials,
    int M, int N, int K)
{
    __shared__ unsigned short AsF[2 * BM * BK];   // 16 KB (buf stride 4096 shorts)
    __shared__ unsigned short BsF[2 * BN * BK];   // 16 KB

    const int nwg = gridDim.x;
    const int ob = blockIdx.x;
    const int bid = (nwg % 8 == 0) ? ((ob % 8) * (nwg / 8) + ob / 8) : ob;  // T1
    const int ntiles = N / BN;
    const int mt = bid / ntiles;
    const int nt = bid % ntiles;
    const int row0 = mt * BM;
    const int col0 = nt * BN;
    const int t = threadIdx.x;
    const int lane = t & 63;
    const int wave = t >> 6;
    const int wm = wave >> 1;             // 2x2 wave grid; per-wave 64x64 out
    const int wn = wave & 1;
    const int fr = lane & 15;
    const int fq = lane >> 4;

    // staging: thread t -> row tr (0..63, second chunk +64), 16B slot tc (0..3);
    // source slot pre-swizzled: cs = tc ^ (tr&3). Row&3 == tr&3 for both chunks.
    const int tr = t >> 2;                // 0..63
    const int tc = t & 3;                 // 16B slot 0..3
    const int cs = tc ^ (tr & 3);         // swizzled global slot

    // loop-invariant LDS read offsets (elements). slot' = fq ^ (row&3), row&3=fr&3.
    const int slot = (fq ^ (fr & 3)) * 8;
    const int ofsA = (wm * 64 + fr) * BK + slot;   // + mi*512
    const int ofsB = (wn * 64 + fr) * BK + slot;   // + ni*512

    f32x4 acc[4][4];
#pragma unroll
    for (int m = 0; m < 4; ++m)
#pragma unroll
        for (int n = 0; n < 4; ++n)
            acc[m][n] = (f32x4){0.f, 0.f, 0.f, 0.f};

    // per-thread source pointers (advance by BK per staged tile)
    const unsigned short* aSrc = Abf + (size_t)(row0 + tr) * K + cs * 8;
    const unsigned short* bSrc = Bbf + (size_t)(col0 + tr) * K + cs * 8;
    unsigned short* aDstC = &AsF[t * 8];   // t*16 bytes within buf 0
    unsigned short* bDstC = &BsF[t * 8];

#define STAGE(BUF) do {                                                                      \
    __builtin_amdgcn_global_load_lds((const AS1 void*)(aSrc),                                \
                                     (AS3 void*)(aDstC + (BUF) * 4096), 16, 0, 0);           \
    __builtin_amdgcn_global_load_lds((const AS1 void*)(aSrc + (size_t)64 * K),               \
                                     (AS3 void*)(aDstC + (BUF) * 4096 + 2048), 16, 0, 0);    \
    __builtin_amdgcn_global_load_lds((const AS1 void*)(bSrc),                                \
                                     (AS3 void*)(bDstC + (BUF) * 4096), 16, 0, 0);           \
    __builtin_amdgcn_global_load_lds((const AS1 void*)(bSrc + (size_t)64 * K),               \
                                     (AS3 void*)(bDstC + (BUF) * 4096 + 2048), 16, 0, 0);    \
    aSrc += BK; bSrc += BK;                                                                  \
} while (0)

// One K=32 tile: 8 ds_read_b128 (invariant bases + imm offsets) + 16 MFMA.
#define MFMA_TILE(BUF) do {                                                                  \
    bf16x8 af_[4], bv_[4];                                                                   \
    _Pragma("unroll")                                                                        \
    for (int mi_ = 0; mi_ < 4; ++mi_)                                                        \
        af_[mi_] = *(const bf16x8*)(AsF + (BUF) * 4096 + ofsA + mi_ * 512);                  \
    _Pragma("unroll")                                                                        \
    for (int ni_ = 0; ni_ < 4; ++ni_)                                                        \
        bv_[ni_] = *(const bf16x8*)(BsF + (BUF) * 4096 + ofsB + ni_ * 512);                  \
    __builtin_amdgcn_s_setprio(1);                                                           \
    _Pragma("unroll")                                                                        \
    for (int mi_ = 0; mi_ < 4; ++mi_)                                                        \
    _Pragma("unroll")                                                                        \
    for (int ni_ = 0; ni_ < 4; ++ni_)                                                        \
        acc[mi_][ni_] = __builtin_amdgcn_mfma_f32_16x16x32_bf16(                             \
            af_[mi_], bv_[ni_], acc[mi_][ni_], 0, 0, 0);                                     \
    __builtin_amdgcn_s_setprio(0);                                                           \
} while (0)

    const int nk = K / BK;          // even (guarded in launch)
    const int nk2 = nk >> 1;
    STAGE(0);                        // tile 0 -> buf 0

    for (int i = 0; i < nk2; ++i) {
        // half A: compute buf0 (tile 2i), stage tile 2i+1 -> buf1
        STAGE(1);
        WAITV4();                    // retires tile 2i's 4 loads (oldest in FIFO)
        BARRIER();
        MFMA_TILE(0);
        BARRIER();
        // half B: compute buf1 (tile 2i+1), stage tile 2i+2 -> buf0
        if (i + 1 < nk2) {
            STAGE(0);
            WAITV4();                // retires tile 2i+1's 4 loads
        } else {
            WAITV0();
        }
        BARRIER();
        MFMA_TILE(1);
        BARRIER();
    }

#undef STAGE
#undef MFMA_TILE

    // Fused epilogue (R11 form; R12's LDS-transpose variant regressed).
    // C/D frag layout: col=lane&15, row=(lane>>4)*4+reg.
    // block row = wm*64 + m*16 + fq*4 + j ; block col = wn*64 + n*16 + fr
    float vsum = 0.f, ssum = 0.f;
#pragma unroll
    for (int n = 0; n < 4; ++n) {
        const int z = col0 + wn * 64 + n * 16 + fr;
        const float idg = invdeg[z];
        const float hnb = hasnb[z];
#pragma unroll
        for (int m = 0; m < 4; ++m) {
            const int rb = row0 + wm * 64 + m * 16 + fq * 4;
#pragma unroll
            for (int j = 0; j < 4; ++j) {
                const size_t idx = (size_t)(rb + j) * N + z;
                float avg = acc[m][n][j] * idg;
                float c = bf2f(Abf[idx]);          // bf16 ctemps (saves 1/3 fetch)
                float p = preds[idx];
                float tg = targets[idx];
                float x = (c - avg) * (p - c);
                vsum += softplus_f(x) * hnb;
                ssum += smooth_l1_f(p - tg);
            }
        }
    }
    for (int o = 32; o; o >>= 1) { vsum += __shfl_down(vsum, o); ssum += __shfl_down(ssum, o); }
    __shared__ float rv[4], rsm[4];
    if (lane == 0) { rv[wave] = vsum; rsm[wave] = ssum; }
    __syncthreads();
    if (t == 0) {
        partials[2 * (size_t)ob]     = rv[0] + rv[1] + rv[2] + rv[3];
        partials[2 * (size_t)ob + 1] = rsm[0] + rsm[1] + rsm[2] + rsm[3];
    }
}

// ---------------------------------------------------------------------------
// Kernel 3: deterministic fixed-order final reduction
__global__ void k_finalize(const float* __restrict__ partials, int nblk,
                           float* __restrict__ out, float invBZ) {
    __shared__ float sv[256], ss[256];
    int t = threadIdx.x;
    float v = 0.f, s = 0.f;
    for (int i = t; i < nblk; i += 256) { v += partials[2 * (size_t)i]; s += partials[2 * (size_t)i + 1]; }
    sv[t] = v; ss[t] = s;
    __syncthreads();
    for (int o = 128; o; o >>= 1) {
        if (t < o) { sv[t] += sv[t + o]; ss[t] += ss[t + o]; }
        __syncthreads();
    }
    if (t == 0) {
        float phys = sv[0] * invBZ;
        float pred = ss[0] * invBZ;
        out[0] = pred + LAMBDA_PHY * phys;
        out[1] = phys;
    }
}

// ---------------------------------------------------------------------------
// Fallback path (only if ws too small / odd shapes): fp32, atomics into ws[0..1]
__global__ void k_zero2(float* p) { if (threadIdx.x < 2) p[threadIdx.x] = 0.f; }

__global__ void k_fallback(const float* __restrict__ preds, const float* __restrict__ targets,
                           const float* __restrict__ ctemps, const int* __restrict__ adj,
                           float* __restrict__ acc2, int B, int Z) {
    extern __shared__ float crow[];
    int nzb = (Z + 255) / 256;
    int b = blockIdx.x / nzb;
    int zb = blockIdx.x % nzb;
    int t = threadIdx.x;
    const float* cr = ctemps + (size_t)b * Z;
    for (int n = t; n < Z; n += 256) crow[n] = cr[n];
    __syncthreads();
    int z = zb * 256 + t;
    float vsum = 0.f, ssum = 0.f;
    if (z < Z) {
        const int* arow = adj + (size_t)z * Z;
        float sum = 0.f; int deg = 0;
        for (int n = 0; n < Z; ++n) {
            if (arow[n] > 0) { sum += crow[n]; ++deg; }
        }
        float avg = (deg > 0) ? sum / (float)deg : 0.f;
        float c = crow[z];
        size_t idx = (size_t)b * Z + z;
        float p = preds[idx];
        float x = (c - avg) * (p - c);
        vsum = (deg > 0) ? softplus_f(x) : 0.f;
        ssum = smooth_l1_f(p - targets[idx]);
    }
    for (int o = 32; o; o >>= 1) { vsum += __shfl_down(vsum, o); ssum += __shfl_down(ssum, o); }
    __shared__ float rv[4], rs2[4];
    int lane = t & 63, wave = t >> 6;
    if (lane == 0) { rv[wave] = vsum; rs2[wave] = ssum; }
    __syncthreads();
    if (t == 0) {
        atomicAdd(&acc2[0], rv[0] + rv[1] + rv[2] + rv[3]);
        atomicAdd(&acc2[1], rs2[0] + rs2[1] + rs2[2] + rs2[3]);
    }
}

// ---------------------------------------------------------------------------
extern "C" void kernel_launch(void* const* d_in, const int* in_sizes, int n_in,
                              void* d_out, int out_size, void* d_ws, size_t ws_size,
                              hipStream_t stream) {
    const float* preds   = (const float*)d_in[0];
    const float* targets = (const float*)d_in[1];
    const float* ctemps  = (const float*)d_in[2];
    const int*   adj     = (const int*)d_in[3];
    float* out = (float*)d_out;

    long zz = in_sizes[3];
    int Z = (int)llround(sqrt((double)zz));
    int B = in_sizes[1] / Z;

    size_t off = 0;
    size_t maskOff = off; off += (size_t)Z * Z * 2;
    size_t cbfOff  = off; off += (size_t)B * Z * 2;
    size_t idgOff  = off; off += (size_t)Z * 4;
    size_t hnbOff  = off; off += (size_t)Z * 4;
    int nblk = (Z > 0 && B > 0 && (B % BM) == 0 && (Z % BN) == 0) ? (B / BM) * (Z / BN) : 0;
    size_t partOff = off; off += (size_t)(nblk > 0 ? nblk : 1) * 2 * 4;

    bool main_ok = (B % BM == 0) && (Z % BN == 0) && (Z % BK == 0) &&
                   (((Z / BK) % 2) == 0) && ((B * Z) % 8 == 0) && (ws_size >= off);

    float invBZ = (float)(1.0 / ((double)B * (double)Z));

    if (main_ok) {
        char* ws = (char*)d_ws;
        unsigned short* maskbf = (unsigned short*)(ws + maskOff);
        unsigned short* cbf    = (unsigned short*)(ws + cbfOff);
        float* idg      = (float*)(ws + idgOff);
        float* hnb      = (float*)(ws + hnbOff);
        float* partials = (float*)(ws + partOff);

        long n8 = (long)B * Z / 8;
        int ncb = 2048;
        k_prepconv<<<Z + ncb, 256, 0, stream>>>(adj, maskbf, idg, hnb, Z,
                                                ctemps, (uint4*)cbf, n8, ncb);
        k_gemm<<<nblk, NT, 0, stream>>>(cbf, maskbf, preds, targets, idg, hnb, partials, B, Z, Z);
        k_finalize<<<1, 256, 0, stream>>>(partials, nblk, out, invBZ);
    } else {
        float* acc2 = (float*)d_ws;
        k_zero2<<<1, 64, 0, stream>>>(acc2);
        int nzb = (Z + 255) / 256;
        k_fallback<<<B * nzb, 256, (size_t)Z * 4, stream>>>(preds, targets, ctemps, adj, acc2, B, Z);
        k_finalize<<<1, 256, 0, stream>>>(acc2, 1, out, invBZ);
    }
}

// Round 14
// 202.078 us; speedup vs baseline: 1.7519x; 1.7519x over previous
//
#include <hip/hip_runtime.h>
#include <hip/hip_bf16.h>
#include <cmath>

#define BETA 0.3f
#define LAMBDA_PHY 0.15f

#define BM 128
#define BN 128
#define BKE 128          // K elems per tile (fp8 -> 128 B rows, 8x16B slots)
#define NT 512

typedef float f32x4 __attribute__((ext_vector_type(4)));

#define AS1 __attribute__((address_space(1)))
#define AS3 __attribute__((address_space(3)))

#define FENCE() asm volatile("" ::: "memory")
#define BARRIER() do { FENCE(); __builtin_amdgcn_s_barrier(); FENCE(); } while (0)
#define WAITV4() asm volatile("s_waitcnt vmcnt(4)" ::: "memory")
#define WAITV0() asm volatile("s_waitcnt vmcnt(0)" ::: "memory")

__device__ __forceinline__ float softplus_f(float x) {
    return fmaxf(x, 0.0f) + __logf(1.0f + __expf(-fabsf(x)));
}

__device__ __forceinline__ float smooth_l1_f(float d) {
    float ad = fabsf(d);
    return (ad < BETA) ? (0.5f / BETA) * d * d : (ad - 0.5f * BETA);
}

// e4m3fn encode (RNE, saturating) / decode — exact bit manipulation.
__device__ __forceinline__ unsigned f_e4m3(float f) {
    unsigned u = __builtin_bit_cast(unsigned, f);
    unsigned s = (u >> 24) & 0x80u;
    unsigned ab = u & 0x7fffffffu;
    float a = __builtin_bit_cast(float, ab);
    if (a >= 448.f) return s | 0x7Eu;
    if (a < 0.015625f) {                       // below min normal 2^-6 -> subnormal
        int q = (int)rintf(a * 512.f);         // lsb 2^-9; q==8 -> 0x08 == 2^-6
        return s | (unsigned)q;
    }
    unsigned r = ab + 0x7FFFFu + ((ab >> 20) & 1u);   // RNE at 3 mantissa bits
    unsigned ee = (r >> 23) - 120u;                    // e-127+7
    unsigned m = (r >> 20) & 7u;
    return s | (ee << 3) | m;
}

__device__ __forceinline__ float e4m3_f(unsigned v) {
    unsigned em = v & 0x7fu;
    float nrm = __builtin_bit_cast(float, (em << 20) + 0x3C000000u);
    float sub = (float)em * 0.001953125f;      // em * 2^-9
    float r = (em >= 8u) ? nrm : sub;
    unsigned sb = (v & 0x80u) << 24;
    return __builtin_bit_cast(float, __builtin_bit_cast(unsigned, r) | sb);
}

// ---------------------------------------------------------------------------
// Kernel 1 (fused): blocks [0,Z): adjacency row -> e4m3 mask + invdeg + hasnb.
//                   blocks [Z,Z+ncb): ctemps fp32 -> e4m3 (16 elems/thread).
__global__ void k_prepconv(const int* __restrict__ adj, unsigned char* __restrict__ maskf8,
                           float* __restrict__ invdeg, float* __restrict__ hasnb, int Z,
                           const float* __restrict__ src, uint4* __restrict__ dst,
                           long n16, int ncb) {
    int t = threadIdx.x;
    if ((int)blockIdx.x < Z) {
        int z = blockIdx.x;
        const int* row = adj + (size_t)z * Z;
        unsigned char* mrow = maskf8 + (size_t)z * Z;
        int cnt = 0;
        for (int n = t; n < Z; n += blockDim.x) {
            int a = (row[n] > 0);
            mrow[n] = a ? (unsigned char)0x38 : (unsigned char)0;   // e4m3 1.0 / 0.0
            cnt += a;
        }
        for (int o = 32; o; o >>= 1) cnt += __shfl_down(cnt, o);
        __shared__ int rs[4];
        int lane = t & 63, wave = t >> 6;
        if (lane == 0) rs[wave] = cnt;
        __syncthreads();
        if (t == 0) {
            int deg = rs[0] + rs[1] + rs[2] + rs[3];
            invdeg[z] = (deg > 0) ? 1.0f / (float)deg : 1.0f;
            hasnb[z]  = (deg > 0) ? 1.0f : 0.0f;
        }
    } else {
        long i = (long)(blockIdx.x - Z) * blockDim.x + t;
        long stride = (long)ncb * blockDim.x;
        for (; i < n16; i += stride) {
            const float4* s = (const float4*)(src + i * 16);
            uint4 o;
            unsigned w[4];
#pragma unroll
            for (int q = 0; q < 4; ++q) {
                float4 v = s[q];
                w[q] = f_e4m3(v.x) | (f_e4m3(v.y) << 8) | (f_e4m3(v.z) << 16) | (f_e4m3(v.w) << 24);
            }
            o.x = w[0]; o.y = w[1]; o.z = w[2]; o.w = w[3];
            dst[i] = o;
        }
    }
}

// ---------------------------------------------------------------------------
// Kernel 2: 128x128 fp8(e4m3) GEMM, BK=128 elems, 8 waves (2x4), per-wave
// 64x32 out, 2 blocks/CU. Identical structure to the bf16 R10 champion —
// rows are 128 B in both (8x16B slots), so the proven conflict-free XOR
// swizzle is unchanged. fp8 halves LDS bytes (ds_read_b64), halves staging
// fetch, and halves barriers/vmcnt waits (16 K-tiles instead of 32).
// mfma_f32_16x16x32_fp8_fp8: A/B = 8 fp8/lane (i64), same C/D layout as bf16.
__global__ __launch_bounds__(NT, 4) void k_gemm(
    const unsigned char* __restrict__ Af8,    // [M][K] e4m3 ctemps
    const unsigned char* __restrict__ Bf8,    // [N][K] e4m3 mask
    const float* __restrict__ preds,
    const float* __restrict__ targets,
    const float* __restrict__ invdeg,
    const float* __restrict__ hasnb,
    float* __restrict__ partials,
    int M, int N, int K)
{
    __shared__ __align__(16) unsigned char AsF[2 * BM * BKE];   // 32 KB
    __shared__ __align__(16) unsigned char BsF[2 * BN * BKE];   // 32 KB

    const int nwg = gridDim.x;
    const int ob = blockIdx.x;
    const int bid = (nwg % 8 == 0) ? ((ob % 8) * (nwg / 8) + ob / 8) : ob;  // T1
    const int ntiles = N / BN;
    const int mt = bid / ntiles;
    const int nt = bid % ntiles;
    const int row0 = mt * BM;
    const int col0 = nt * BN;
    const int t = threadIdx.x;
    const int lane = t & 63;
    const int wave = t >> 6;
    const int wm = wave >> 2;             // 2x4 wave grid; per-wave 64x32 out
    const int wn = wave & 3;
    const int fr = lane & 15;
    const int fq = lane >> 4;
    const int fr7 = fr & 7;

    // staging: thread t -> row tr (0..63, +64 2nd chunk), 16B slot tc (0..7);
    // source slot pre-swizzled (T2): cs = tc ^ (tr&7). Same geometry as bf16.
    const int tr = t >> 3;
    const int tc = t & 7;
    const int cs = tc ^ (tr & 7);

    // loop-invariant LDS read byte-offsets. Lane reads 8 B at K-byte
    // kk*32 + fq*8 -> 16B slot (2kk + (fq>>1)) ^ (row&7), half fq&1.
    int ofsA[4], ofsB[4];
#pragma unroll
    for (int kk = 0; kk < 4; ++kk) {
        const int sp = (((2 * kk + (fq >> 1)) ^ fr7) << 4) + (fq & 1) * 8;
        ofsA[kk] = (wm * 64 + fr) * BKE + sp;   // + mi*2048 (16 rows)
        ofsB[kk] = (wn * 32 + fr) * BKE + sp;   // + ni*2048
    }

    f32x4 acc[4][2];
#pragma unroll
    for (int m = 0; m < 4; ++m)
#pragma unroll
        for (int n = 0; n < 2; ++n)
            acc[m][n] = (f32x4){0.f, 0.f, 0.f, 0.f};

    // per-thread byte source pointers (advance by BKE bytes per staged tile)
    const unsigned char* aSrc = Af8 + (size_t)(row0 + tr) * K + cs * 16;
    const unsigned char* bSrc = Bf8 + (size_t)(col0 + tr) * K + cs * 16;
    unsigned char* aDstC = &AsF[t * 16];
    unsigned char* bDstC = &BsF[t * 16];

#define STAGE(BUF) do {                                                                      \
    __builtin_amdgcn_global_load_lds((const AS1 void*)(aSrc),                                \
                                     (AS3 void*)(aDstC + (BUF) * 16384), 16, 0, 0);          \
    __builtin_amdgcn_global_load_lds((const AS1 void*)(aSrc + (size_t)64 * K),               \
                                     (AS3 void*)(aDstC + (BUF) * 16384 + 8192), 16, 0, 0);   \
    __builtin_amdgcn_global_load_lds((const AS1 void*)(bSrc),                                \
                                     (AS3 void*)(bDstC + (BUF) * 16384), 16, 0, 0);          \
    __builtin_amdgcn_global_load_lds((const AS1 void*)(bSrc + (size_t)64 * K),               \
                                     (AS3 void*)(bDstC + (BUF) * 16384 + 8192), 16, 0, 0);   \
    aSrc += BKE; bSrc += BKE;                                                                \
} while (0)

// One K=128 tile: 4 kk steps x {6 ds_read_b64 + 8 MFMA}.
#define MFMA_TILE(BUF) do {                                                                  \
    _Pragma("unroll")                                                                        \
    for (int kk_ = 0; kk_ < 4; ++kk_) {                                                      \
        long af_[4], bv_[2];                                                                 \
        _Pragma("unroll")                                                                    \
        for (int mi_ = 0; mi_ < 4; ++mi_)                                                    \
            af_[mi_] = *(const long*)(AsF + (BUF) * 16384 + ofsA[kk_] + mi_ * 2048);         \
        _Pragma("unroll")                                                                    \
        for (int ni_ = 0; ni_ < 2; ++ni_)                                                    \
            bv_[ni_] = *(const long*)(BsF + (BUF) * 16384 + ofsB[kk_] + ni_ * 2048);         \
        __builtin_amdgcn_s_setprio(1);                                                       \
        _Pragma("unroll")                                                                    \
        for (int mi_ = 0; mi_ < 4; ++mi_)                                                    \
        _Pragma("unroll")                                                                    \
        for (int ni_ = 0; ni_ < 2; ++ni_)                                                    \
            acc[mi_][ni_] = __builtin_amdgcn_mfma_f32_16x16x32_fp8_fp8(                      \
                af_[mi_], bv_[ni_], acc[mi_][ni_], 0, 0, 0);                                 \
        __builtin_amdgcn_s_setprio(0);                                                       \
    }                                                                                        \
} while (0)

    const int nk = K / BKE;         // 16 at Z=2048; even (guarded)
    const int nk2 = nk >> 1;
    STAGE(0);                        // tile 0 -> buf 0

    for (int i = 0; i < nk2; ++i) {
        STAGE(1);
        WAITV4();                    // retires tile 2i's 4 loads (oldest in FIFO)
        BARRIER();
        MFMA_TILE(0);
        BARRIER();
        if (i + 1 < nk2) {
            STAGE(0);
            WAITV4();
        } else {
            WAITV0();
        }
        BARRIER();
        MFMA_TILE(1);
        BARRIER();
    }

#undef STAGE
#undef MFMA_TILE

    // Fused epilogue (R10 form). C/D layout: col=lane&15, row=(lane>>4)*4+reg.
    // block row = wm*64 + m*16 + fq*4 + j ; block col = wn*32 + n*16 + fr
    float vsum = 0.f, ssum = 0.f;
#pragma unroll
    for (int n = 0; n < 2; ++n) {
        const int z = col0 + wn * 32 + n * 16 + fr;
        const float idg = invdeg[z];
        const float hnb = hasnb[z];
#pragma unroll
        for (int m = 0; m < 4; ++m) {
            const int rb = row0 + wm * 64 + m * 16 + fq * 4;
#pragma unroll
            for (int j = 0; j < 4; ++j) {
                const size_t idx = (size_t)(rb + j) * N + z;
                float avg = acc[m][n][j] * idg;
                float c = e4m3_f(Af8[idx]);
                float p = preds[idx];
                float tg = targets[idx];
                float x = (c - avg) * (p - c);
                vsum += softplus_f(x) * hnb;
                ssum += smooth_l1_f(p - tg);
            }
        }
    }
    for (int o = 32; o; o >>= 1) { vsum += __shfl_down(vsum, o); ssum += __shfl_down(ssum, o); }
    __shared__ float rv[8], rsm[8];
    if (lane == 0) { rv[wave] = vsum; rsm[wave] = ssum; }
    __syncthreads();
    if (t == 0) {
        float v = 0.f, s = 0.f;
#pragma unroll
        for (int w = 0; w < 8; ++w) { v += rv[w]; s += rsm[w]; }
        partials[2 * (size_t)ob]     = v;
        partials[2 * (size_t)ob + 1] = s;
    }
}

// ---------------------------------------------------------------------------
// Kernel 3: deterministic fixed-order final reduction
__global__ void k_finalize(const float* __restrict__ partials, int nblk,
                           float* __restrict__ out, float invBZ) {
    __shared__ float sv[256], ss[256];
    int t = threadIdx.x;
    float v = 0.f, s = 0.f;
    for (int i = t; i < nblk; i += 256) { v += partials[2 * (size_t)i]; s += partials[2 * (size_t)i + 1]; }
    sv[t] = v; ss[t] = s;
    __syncthreads();
    for (int o = 128; o; o >>= 1) {
        if (t < o) { sv[t] += sv[t + o]; ss[t] += ss[t + o]; }
        __syncthreads();
    }
    if (t == 0) {
        float phys = sv[0] * invBZ;
        float pred = ss[0] * invBZ;
        out[0] = pred + LAMBDA_PHY * phys;
        out[1] = phys;
    }
}

// ---------------------------------------------------------------------------
// Fallback path (only if ws too small / odd shapes): fp32, atomics into ws[0..1]
__global__ void k_zero2(float* p) { if (threadIdx.x < 2) p[threadIdx.x] = 0.f; }

__global__ void k_fallback(const float* __restrict__ preds, const float* __restrict__ targets,
                           const float* __restrict__ ctemps, const int* __restrict__ adj,
                           float* __restrict__ acc2, int B, int Z) {
    extern __shared__ float crow[];
    int nzb = (Z + 255) / 256;
    int b = blockIdx.x / nzb;
    int zb = blockIdx.x % nzb;
    int t = threadIdx.x;
    const float* cr = ctemps + (size_t)b * Z;
    for (int n = t; n < Z; n += 256) crow[n] = cr[n];
    __syncthreads();
    int z = zb * 256 + t;
    float vsum = 0.f, ssum = 0.f;
    if (z < Z) {
        const int* arow = adj + (size_t)z * Z;
        float sum = 0.f; int deg = 0;
        for (int n = 0; n < Z; ++n) {
            if (arow[n] > 0) { sum += crow[n]; ++deg; }
        }
        float avg = (deg > 0) ? sum / (float)deg : 0.f;
        float c = crow[z];
        size_t idx = (size_t)b * Z + z;
        float p = preds[idx];
        float x = (c - avg) * (p - c);
        vsum = (deg > 0) ? softplus_f(x) : 0.f;
        ssum = smooth_l1_f(p - targets[idx]);
    }
    for (int o = 32; o; o >>= 1) { vsum += __shfl_down(vsum, o); ssum += __shfl_down(ssum, o); }
    __shared__ float rv[4], rs2[4];
    int lane = t & 63, wave = t >> 6;
    if (lane == 0) { rv[wave] = vsum; rs2[wave] = ssum; }
    __syncthreads();
    if (t == 0) {
        atomicAdd(&acc2[0], rv[0] + rv[1] + rv[2] + rv[3]);
        atomicAdd(&acc2[1], rs2[0] + rs2[1] + rs2[2] + rs2[3]);
    }
}

// ---------------------------------------------------------------------------
extern "C" void kernel_launch(void* const* d_in, const int* in_sizes, int n_in,
                              void* d_out, int out_size, void* d_ws, size_t ws_size,
                              hipStream_t stream) {
    const float* preds   = (const float*)d_in[0];
    const float* targets = (const float*)d_in[1];
    const float* ctemps  = (const float*)d_in[2];
    const int*   adj     = (const int*)d_in[3];
    float* out = (float*)d_out;

    long zz = in_sizes[3];
    int Z = (int)llround(sqrt((double)zz));
    int B = in_sizes[1] / Z;

    size_t off = 0;
    size_t maskOff = off; off += (size_t)Z * Z;          // fp8 mask
    size_t cf8Off  = off; off += (size_t)B * Z;          // fp8 ctemps
    size_t idgOff  = off; off += (size_t)Z * 4;
    size_t hnbOff  = off; off += (size_t)Z * 4;
    int nblk = (Z > 0 && B > 0 && (B % BM) == 0 && (Z % BN) == 0) ? (B / BM) * (Z / BN) : 0;
    size_t partOff = off; off += (size_t)(nblk > 0 ? nblk : 1) * 2 * 4;

    bool main_ok = (B % BM == 0) && (Z % BN == 0) && (Z % BKE == 0) &&
                   (((Z / BKE) % 2) == 0) && ((B * Z) % 16 == 0) && (ws_size >= off);

    float invBZ = (float)(1.0 / ((double)B * (double)Z));

    if (main_ok) {
        char* ws = (char*)d_ws;
        unsigned char* maskf8 = (unsigned char*)(ws + maskOff);
        unsigned char* cf8    = (unsigned char*)(ws + cf8Off);
        float* idg      = (float*)(ws + idgOff);
        float* hnb      = (float*)(ws + hnbOff);
        float* partials = (float*)(ws + partOff);

        long n16 = (long)B * Z / 16;
        int ncb = 2048;
        k_prepconv<<<Z + ncb, 256, 0, stream>>>(adj, maskf8, idg, hnb, Z,
                                                ctemps, (uint4*)cf8, n16, ncb);
        k_gemm<<<nblk, NT, 0, stream>>>(cf8, maskf8, preds, targets, idg, hnb, partials, B, Z, Z);
        k_finalize<<<1, 256, 0, stream>>>(partials, nblk, out, invBZ);
    } else {
        float* acc2 = (float*)d_ws;
        k_zero2<<<1, 64, 0, stream>>>(acc2);
        int nzb = (Z + 255) / 256;
        k_fallback<<<B * nzb, 256, (size_t)Z * 4, stream>>>(preds, targets, ctemps, adj, acc2, B, Z);
        k_finalize<<<1, 256, 0, stream>>>(acc2, 1, out, invBZ);
    }
}

// Round 15
// 199.134 us; speedup vs baseline: 1.7778x; 1.0148x over previous
//
#include <hip/hip_runtime.h>
#include <hip/hip_bf16.h>
#include <cmath>

#define BETA 0.3f
#define LAMBDA_PHY 0.15f

#define BM 128
#define BN 128
#define BKE 128          // K elems per tile (fp8 -> 128 B rows, 8x16B slots)
#define NT 512

typedef float f32x4 __attribute__((ext_vector_type(4)));
typedef long  i64x2 __attribute__((ext_vector_type(2)));

#define AS1 __attribute__((address_space(1)))
#define AS3 __attribute__((address_space(3)))

#define FENCE() asm volatile("" ::: "memory")
#define BARRIER() do { FENCE(); __builtin_amdgcn_s_barrier(); FENCE(); } while (0)
#define WAITV4() asm volatile("s_waitcnt vmcnt(4)" ::: "memory")
#define WAITV0() asm volatile("s_waitcnt vmcnt(0)" ::: "memory")

__device__ __forceinline__ float softplus_f(float x) {
    return fmaxf(x, 0.0f) + __logf(1.0f + __expf(-fabsf(x)));
}

__device__ __forceinline__ float smooth_l1_f(float d) {
    float ad = fabsf(d);
    return (ad < BETA) ? (0.5f / BETA) * d * d : (ad - 0.5f * BETA);
}

// e4m3fn encode (RNE, saturating) — exact bit manipulation.
__device__ __forceinline__ unsigned f_e4m3(float f) {
    unsigned u = __builtin_bit_cast(unsigned, f);
    unsigned s = (u >> 24) & 0x80u;
    unsigned ab = u & 0x7fffffffu;
    float a = __builtin_bit_cast(float, ab);
    if (a >= 448.f) return s | 0x7Eu;
    if (a < 0.015625f) {                       // below min normal 2^-6 -> subnormal
        int q = (int)rintf(a * 512.f);         // lsb 2^-9; q==8 -> 0x08 == 2^-6
        return s | (unsigned)q;
    }
    unsigned r = ab + 0x7FFFFu + ((ab >> 20) & 1u);   // RNE at 3 mantissa bits
    unsigned ee = (r >> 23) - 120u;                    // e-127+7
    unsigned m = (r >> 20) & 7u;
    return s | (ee << 3) | m;
}

// ---------------------------------------------------------------------------
// Kernel 1 (fused): blocks [0,Z): adjacency row -> e4m3 mask + invdeg + hasnb.
//                   blocks [Z,Z+ncb): ctemps fp32 -> e4m3 (16 elems/thread).
__global__ void k_prepconv(const int* __restrict__ adj, unsigned char* __restrict__ maskf8,
                           float* __restrict__ invdeg, float* __restrict__ hasnb, int Z,
                           const float* __restrict__ src, uint4* __restrict__ dst,
                           long n16, int ncb) {
    int t = threadIdx.x;
    if ((int)blockIdx.x < Z) {
        int z = blockIdx.x;
        const int* row = adj + (size_t)z * Z;
        unsigned char* mrow = maskf8 + (size_t)z * Z;
        int cnt = 0;
        for (int n = t; n < Z; n += blockDim.x) {
            int a = (row[n] > 0);
            mrow[n] = a ? (unsigned char)0x38 : (unsigned char)0;   // e4m3 1.0 / 0.0
            cnt += a;
        }
        for (int o = 32; o; o >>= 1) cnt += __shfl_down(cnt, o);
        __shared__ int rs[4];
        int lane = t & 63, wave = t >> 6;
        if (lane == 0) rs[wave] = cnt;
        __syncthreads();
        if (t == 0) {
            int deg = rs[0] + rs[1] + rs[2] + rs[3];
            invdeg[z] = (deg > 0) ? 1.0f / (float)deg : 1.0f;
            hasnb[z]  = (deg > 0) ? 1.0f : 0.0f;
        }
    } else {
        long i = (long)(blockIdx.x - Z) * blockDim.x + t;
        long stride = (long)ncb * blockDim.x;
        for (; i < n16; i += stride) {
            const float4* s = (const float4*)(src + i * 16);
            uint4 o;
            unsigned w[4];
#pragma unroll
            for (int q = 0; q < 4; ++q) {
                float4 v = s[q];
                w[q] = f_e4m3(v.x) | (f_e4m3(v.y) << 8) | (f_e4m3(v.z) << 16) | (f_e4m3(v.w) << 24);
            }
            o.x = w[0]; o.y = w[1]; o.z = w[2]; o.w = w[3];
            dst[i] = o;
        }
    }
}

// ---------------------------------------------------------------------------
// Kernel 2: 128x128 fp8(e4m3) GEMM, BK=128 elems, 8 waves (2x4), per-wave
// 64x32 out, 2 blocks/CU. R15 fix vs R14: fragment reads are ds_read_b128
// (R14's b64 + 8B-half pattern caused 2.5e7 bank conflicts). K-chunk
// remapping (sum over K is order-free): lane reads 16B at logical slot
// (fq+4p); halves h=0/1 feed MFMA calls (p,h). Instruction (p,h) covers
// K-chunks {2(fq+4p)+h}, disjoint, union = K=128; A and B use the SAME
// mapping -> valid. XOR slot swizzle identical to the verified bf16 kernel
// (uniform 8 accesses/bank = conflict-free). 12 b128 reads/tile/wave.
__global__ __launch_bounds__(NT, 4) void k_gemm(
    const unsigned char* __restrict__ Af8,    // [M][K] e4m3 ctemps
    const unsigned char* __restrict__ Bf8,    // [N][K] e4m3 mask
    const float* __restrict__ preds,
    const float* __restrict__ targets,
    const float* __restrict__ ctemps,         // fp32 (epilogue c — no decode)
    const float* __restrict__ invdeg,
    const float* __restrict__ hasnb,
    float* __restrict__ partials,
    int M, int N, int K)
{
    __shared__ __align__(16) unsigned char AsF[2 * BM * BKE];   // 32 KB
    __shared__ __align__(16) unsigned char BsF[2 * BN * BKE];   // 32 KB

    const int nwg = gridDim.x;
    const int ob = blockIdx.x;
    const int bid = (nwg % 8 == 0) ? ((ob % 8) * (nwg / 8) + ob / 8) : ob;  // T1
    const int ntiles = N / BN;
    const int mt = bid / ntiles;
    const int nt = bid % ntiles;
    const int row0 = mt * BM;
    const int col0 = nt * BN;
    const int t = threadIdx.x;
    const int lane = t & 63;
    const int wave = t >> 6;
    const int wm = wave >> 2;             // 2x4 wave grid; per-wave 64x32 out
    const int wn = wave & 3;
    const int fr = lane & 15;
    const int fq = lane >> 4;
    const int fr7 = fr & 7;

    // staging: thread t -> row tr (0..63, +64 2nd chunk), 16B slot tc (0..7);
    // source slot pre-swizzled (T2): cs = tc ^ (tr&7).
    const int tr = t >> 3;
    const int tc = t & 7;
    const int cs = tc ^ (tr & 7);

    // loop-invariant LDS read byte-offsets: one b128 per (row, p), logical
    // slot fq+4p, physical slot (fq+4p)^(row&7); row&7 == fr&7.
    int ofsA[2], ofsB[2];
#pragma unroll
    for (int p = 0; p < 2; ++p) {
        const int sp = (((fq + 4 * p) ^ fr7) << 4);
        ofsA[p] = (wm * 64 + fr) * BKE + sp;   // + mi*2048 (16 rows)
        ofsB[p] = (wn * 32 + fr) * BKE + sp;   // + ni*2048
    }

    f32x4 acc[4][2];
#pragma unroll
    for (int m = 0; m < 4; ++m)
#pragma unroll
        for (int n = 0; n < 2; ++n)
            acc[m][n] = (f32x4){0.f, 0.f, 0.f, 0.f};

    // per-thread byte source pointers (advance by BKE bytes per staged tile)
    const unsigned char* aSrc = Af8 + (size_t)(row0 + tr) * K + cs * 16;
    const unsigned char* bSrc = Bf8 + (size_t)(col0 + tr) * K + cs * 16;
    unsigned char* aDstC = &AsF[t * 16];
    unsigned char* bDstC = &BsF[t * 16];

#define STAGE(BUF) do {                                                                      \
    __builtin_amdgcn_global_load_lds((const AS1 void*)(aSrc),                                \
                                     (AS3 void*)(aDstC + (BUF) * 16384), 16, 0, 0);          \
    __builtin_amdgcn_global_load_lds((const AS1 void*)(aSrc + (size_t)64 * K),               \
                                     (AS3 void*)(aDstC + (BUF) * 16384 + 8192), 16, 0, 0);   \
    __builtin_amdgcn_global_load_lds((const AS1 void*)(bSrc),                                \
                                     (AS3 void*)(bDstC + (BUF) * 16384), 16, 0, 0);          \
    __builtin_amdgcn_global_load_lds((const AS1 void*)(bSrc + (size_t)64 * K),               \
                                     (AS3 void*)(bDstC + (BUF) * 16384 + 8192), 16, 0, 0);   \
    aSrc += BKE; bSrc += BKE;                                                                \
} while (0)

// One K=128 tile: 2 p-steps x {6 ds_read_b128 + 16 MFMA (h=0 then h=1)}.
#define MFMA_TILE(BUF) do {                                                                  \
    _Pragma("unroll")                                                                        \
    for (int p_ = 0; p_ < 2; ++p_) {                                                         \
        i64x2 af_[4], bv_[2];                                                                \
        _Pragma("unroll")                                                                    \
        for (int mi_ = 0; mi_ < 4; ++mi_)                                                    \
            af_[mi_] = *(const i64x2*)(AsF + (BUF) * 16384 + ofsA[p_] + mi_ * 2048);         \
        _Pragma("unroll")                                                                    \
        for (int ni_ = 0; ni_ < 2; ++ni_)                                                    \
            bv_[ni_] = *(const i64x2*)(BsF + (BUF) * 16384 + ofsB[p_] + ni_ * 2048);         \
        __builtin_amdgcn_s_setprio(1);                                                       \
        _Pragma("unroll")                                                                    \
        for (int mi_ = 0; mi_ < 4; ++mi_)                                                    \
        _Pragma("unroll")                                                                    \
        for (int ni_ = 0; ni_ < 2; ++ni_)                                                    \
            acc[mi_][ni_] = __builtin_amdgcn_mfma_f32_16x16x32_fp8_fp8(                      \
                af_[mi_][0], bv_[ni_][0], acc[mi_][ni_], 0, 0, 0);                           \
        _Pragma("unroll")                                                                    \
        for (int mi_ = 0; mi_ < 4; ++mi_)                                                    \
        _Pragma("unroll")                                                                    \
        for (int ni_ = 0; ni_ < 2; ++ni_)                                                    \
            acc[mi_][ni_] = __builtin_amdgcn_mfma_f32_16x16x32_fp8_fp8(                      \
                af_[mi_][1], bv_[ni_][1], acc[mi_][ni_], 0, 0, 0);                           \
        __builtin_amdgcn_s_setprio(0);                                                       \
    }                                                                                        \
} while (0)

    const int nk = K / BKE;         // 16 at Z=2048; even (guarded)
    const int nk2 = nk >> 1;
    STAGE(0);                        // tile 0 -> buf 0

    for (int i = 0; i < nk2; ++i) {
        STAGE(1);
        WAITV4();                    // retires tile 2i's 4 loads (oldest in FIFO)
        BARRIER();
        MFMA_TILE(0);
        BARRIER();
        if (i + 1 < nk2) {
            STAGE(0);
            WAITV4();
        } else {
            WAITV0();
        }
        BARRIER();
        MFMA_TILE(1);
        BARRIER();
    }

#undef STAGE
#undef MFMA_TILE

    // Fused epilogue. C/D layout: col=lane&15, row=(lane>>4)*4+reg.
    // block row = wm*64 + m*16 + fq*4 + j ; block col = wn*32 + n*16 + fr
    float vsum = 0.f, ssum = 0.f;
#pragma unroll
    for (int n = 0; n < 2; ++n) {
        const int z = col0 + wn * 32 + n * 16 + fr;
        const float idg = invdeg[z];
        const float hnb = hasnb[z];
#pragma unroll
        for (int m = 0; m < 4; ++m) {
            const int rb = row0 + wm * 64 + m * 16 + fq * 4;
#pragma unroll
            for (int j = 0; j < 4; ++j) {
                const size_t idx = (size_t)(rb + j) * N + z;
                float avg = acc[m][n][j] * idg;
                float c = ctemps[idx];               // fp32: no decode VALU
                float p = preds[idx];
                float tg = targets[idx];
                float x = (c - avg) * (p - c);
                vsum += softplus_f(x) * hnb;
                ssum += smooth_l1_f(p - tg);
            }
        }
    }
    for (int o = 32; o; o >>= 1) { vsum += __shfl_down(vsum, o); ssum += __shfl_down(ssum, o); }
    __shared__ float rv[8], rsm[8];
    if (lane == 0) { rv[wave] = vsum; rsm[wave] = ssum; }
    __syncthreads();
    if (t == 0) {
        float v = 0.f, s = 0.f;
#pragma unroll
        for (int w = 0; w < 8; ++w) { v += rv[w]; s += rsm[w]; }
        partials[2 * (size_t)ob]     = v;
        partials[2 * (size_t)ob + 1] = s;
    }
}

// ---------------------------------------------------------------------------
// Kernel 3: deterministic fixed-order final reduction
__global__ void k_finalize(const float* __restrict__ partials, int nblk,
                           float* __restrict__ out, float invBZ) {
    __shared__ float sv[256], ss[256];
    int t = threadIdx.x;
    float v = 0.f, s = 0.f;
    for (int i = t; i < nblk; i += 256) { v += partials[2 * (size_t)i]; s += partials[2 * (size_t)i + 1]; }
    sv[t] = v; ss[t] = s;
    __syncthreads();
    for (int o = 128; o; o >>= 1) {
        if (t < o) { sv[t] += sv[t + o]; ss[t] += ss[t + o]; }
        __syncthreads();
    }
    if (t == 0) {
        float phys = sv[0] * invBZ;
        float pred = ss[0] * invBZ;
        out[0] = pred + LAMBDA_PHY * phys;
        out[1] = phys;
    }
}

// ---------------------------------------------------------------------------
// Fallback path (only if ws too small / odd shapes): fp32, atomics into ws[0..1]
__global__ void k_zero2(float* p) { if (threadIdx.x < 2) p[threadIdx.x] = 0.f; }

__global__ void k_fallback(const float* __restrict__ preds, const float* __restrict__ targets,
                           const float* __restrict__ ctemps, const int* __restrict__ adj,
                           float* __restrict__ acc2, int B, int Z) {
    extern __shared__ float crow[];
    int nzb = (Z + 255) / 256;
    int b = blockIdx.x / nzb;
    int zb = blockIdx.x % nzb;
    int t = threadIdx.x;
    const float* cr = ctemps + (size_t)b * Z;
    for (int n = t; n < Z; n += 256) crow[n] = cr[n];
    __syncthreads();
    int z = zb * 256 + t;
    float vsum = 0.f, ssum = 0.f;
    if (z < Z) {
        const int* arow = adj + (size_t)z * Z;
        float sum = 0.f; int deg = 0;
        for (int n = 0; n < Z; ++n) {
            if (arow[n] > 0) { sum += crow[n]; ++deg; }
        }
        float avg = (deg > 0) ? sum / (float)deg : 0.f;
        float c = crow[z];
        size_t idx = (size_t)b * Z + z;
        float p = preds[idx];
        float x = (c - avg) * (p - c);
        vsum = (deg > 0) ? softplus_f(x) : 0.f;
        ssum = smooth_l1_f(p - targets[idx]);
    }
    for (int o = 32; o; o >>= 1) { vsum += __shfl_down(vsum, o); ssum += __shfl_down(ssum, o); }
    __shared__ float rv[4], rs2[4];
    int lane = t & 63, wave = t >> 6;
    if (lane == 0) { rv[wave] = vsum; rs2[wave] = ssum; }
    __syncthreads();
    if (t == 0) {
        atomicAdd(&acc2[0], rv[0] + rv[1] + rv[2] + rv[3]);
        atomicAdd(&acc2[1], rs2[0] + rs2[1] + rs2[2] + rs2[3]);
    }
}

// ---------------------------------------------------------------------------
extern "C" void kernel_launch(void* const* d_in, const int* in_sizes, int n_in,
                              void* d_out, int out_size, void* d_ws, size_t ws_size,
                              hipStream_t stream) {
    const float* preds   = (const float*)d_in[0];
    const float* targets = (const float*)d_in[1];
    const float* ctemps  = (const float*)d_in[2];
    const int*   adj     = (const int*)d_in[3];
    float* out = (float*)d_out;

    long zz = in_sizes[3];
    int Z = (int)llround(sqrt((double)zz));
    int B = in_sizes[1] / Z;

    size_t off = 0;
    size_t maskOff = off; off += (size_t)Z * Z;          // fp8 mask
    size_t cf8Off  = off; off += (size_t)B * Z;          // fp8 ctemps
    size_t idgOff  = off; off += (size_t)Z * 4;
    size_t hnbOff  = off; off += (size_t)Z * 4;
    int nblk = (Z > 0 && B > 0 && (B % BM) == 0 && (Z % BN) == 0) ? (B / BM) * (Z / BN) : 0;
    size_t partOff = off; off += (size_t)(nblk > 0 ? nblk : 1) * 2 * 4;

    bool main_ok = (B % BM == 0) && (Z % BN == 0) && (Z % BKE == 0) &&
                   (((Z / BKE) % 2) == 0) && ((B * Z) % 16 == 0) && (ws_size >= off);

    float invBZ = (float)(1.0 / ((double)B * (double)Z));

    if (main_ok) {
        char* ws = (char*)d_ws;
        unsigned char* maskf8 = (unsigned char*)(ws + maskOff);
        unsigned char* cf8    = (unsigned char*)(ws + cf8Off);
        float* idg      = (float*)(ws + idgOff);
        float* hnb      = (float*)(ws + hnbOff);
        float* partials = (float*)(ws + partOff);

        long n16 = (long)B * Z / 16;
        int ncb = 2048;
        k_prepconv<<<Z + ncb, 256, 0, stream>>>(adj, maskf8, idg, hnb, Z,
                                                ctemps, (uint4*)cf8, n16, ncb);
        k_gemm<<<nblk, NT, 0, stream>>>(cf8, maskf8, preds, targets, ctemps, idg, hnb,
                                        partials, B, Z, Z);
        k_finalize<<<1, 256, 0, stream>>>(partials, nblk, out, invBZ);
    } else {
        float* acc2 = (float*)d_ws;
        k_zero2<<<1, 64, 0, stream>>>(acc2);
        int nzb = (Z + 255) / 256;
        k_fallback<<<B * nzb, 256, (size_t)Z * 4, stream>>>(preds, targets, ctemps, adj, acc2, B, Z);
        k_finalize<<<1, 256, 0, stream>>>(acc2, 1, out, invBZ);
    }
}